// Round 6
// baseline (34.076 us; speedup 1.0000x reference)
//
#include <hip/hip_runtime.h>
#include <math.h>

#define NTHREADS 512
#define MAXN 4096
#define PER 8            // keys per thread = MAXN / NTHREADS
#define DETS 100
#define CHUNK 256        // per-round selection target
#define CAP 512          // chunk capacity (sort size)
#define NWAVES (NTHREADS / 64)
#define BASE14 0x101FFu  // 0x407FFFFF >> 14 (key32 of score==1.0)

static __device__ __forceinline__ unsigned long long shfl_xor64(unsigned long long x, int m) {
    int lo = __shfl_xor((int)(unsigned)x, m, 64);
    int hi = __shfl_xor((int)(unsigned)(x >> 32), m, 64);
    return ((unsigned long long)(unsigned)hi << 32) | (unsigned)lo;
}
static __device__ __forceinline__ unsigned long long shfl_bc64(unsigned long long x, int src) {
    int lo = __shfl((int)(unsigned)x, src, 64);
    int hi = __shfl((int)(unsigned)(x >> 32), src, 64);
    return ((unsigned long long)(unsigned)hi << 32) | (unsigned)lo;
}
// swizzled histogram slot: bins contiguous per scan-lane but bank-spread
static __device__ __forceinline__ int hloc(int b) { return ((b & 63) << 6) | (b >> 6); }

static __device__ __forceinline__ float iou_f(float ax1, float ay1, float ax2, float ay2, float aar,
                                              float bx1, float by1, float bx2, float by2, float bar) {
#pragma clang fp contract(off)
    float xx1 = fmaxf(ax1, bx1), yy1 = fmaxf(ay1, by1);
    float xx2 = fminf(ax2, bx2), yy2 = fminf(ay2, by2);
    float iw = fmaxf((xx2 - xx1) + 1.0f, 0.0f);
    float ih = fmaxf((yy2 - yy1) + 1.0f, 0.0f);
    float inter = iw * ih;
    return inter / ((aar + bar) - inter);
}

__global__ __launch_bounds__(NTHREADS) void postproc_kernel(
    const float* __restrict__ logits,   // (B,N,2)
    const float* __restrict__ regr,     // (B,N,8)
    const float* __restrict__ props,    // (B,N,4)
    float* __restrict__ out,            // (B,100,5) ++ (B,100) ++ (B,100)
    int B, int N)
{
#pragma clang fp contract(off)
    const int b    = blockIdx.x;
    const int tid  = threadIdx.x;
    const int lane = tid & 63;
    const int wid  = tid >> 6;

    __shared__ unsigned long long keysel[CAP];          // 4 KB
    __shared__ unsigned hist4k[4096];                   // 16 KB (fallback reuses first 2 KB*4)
    __shared__ float bx1s[CAP], by1s[CAP], bx2s[CAP], by2s[CAP], bars[CAP], bscs[CAP]; // 12 KB
    __shared__ float kb[5][DETS + 64];                  // kept boxes
    __shared__ unsigned tmask[64][2];
    __shared__ unsigned supk[64];
    __shared__ int s_kept, s_vcount, s_cnt, s_C, s_bin;
    __shared__ unsigned long long s_prefix, s_T;
    __shared__ int s_target, s_done, s_findkey;

    const float* lg = logits + (size_t)b * N * 2;
    const float* rg = regr   + (size_t)b * N * 8;
    const float* pp = props  + (size_t)b * N * 4;

    // ---------------- Phase A: keys in registers (coalesced loads) ----------------
    unsigned long long v[PER];
    int nval = 0;
#pragma unroll
    for (int s = 0; s < PER; ++s) {
        int a = s * NTHREADS + tid;
        unsigned long long key;
        if (a < N) {
            float2 l = ((const float2*)lg)[a];
            // softmax[:,1] bit-exact: one exp arg is exactly 0 -> e=1
            float zmax = fmaxf(l.x, l.y), zmin = fminf(l.x, l.y);
            float e   = (float)exp((double)(zmin - zmax));
            float den = e + 1.0f;
            float sscore = (l.y >= l.x) ? (1.0f / den) : (e / den);
            bool valid = sscore > 0.05f;
            nval += valid ? 1 : 0;
            float f = valid ? sscore : -1e30f;
            unsigned u = __float_as_uint(f);
            u = (u & 0x80000000u) ? ~u : (u | 0x80000000u);     // monotone float->uint
            key = ((unsigned long long)(~u) << 32) | (unsigned)a; // small key = best
        } else key = ~0ull;
        v[s] = key;
    }

    if (tid == 0) { s_vcount = 0; s_kept = 0; }
    __syncthreads();
    {
        int c = nval;
#pragma unroll
        for (int off = 32; off; off >>= 1) c += __shfl_xor(c, off, 64);
        if (lane == 0) atomicAdd(&s_vcount, c);
    }
    __syncthreads();
    const int V = s_vcount;

    float* obox = out + (size_t)b * DETS * 5;
    float* olab = out + (size_t)B * DETS * 5 + (size_t)b * DETS;
    float* oval = out + (size_t)B * DETS * 5 + (size_t)B * DETS + (size_t)b * DETS;
    const float CLIPV = (float)4.135166556742356;   // log(1000/16)

    int kept = 0, Mdone = 0;

    while (kept < DETS && Mdone < V) {
        int remaining = V - Mdone;
        int tgt = remaining < CHUNK ? remaining : CHUNK;

        // ---- zero phase (hist, keysel prefill, counters) ----
        for (int i = tid; i < 4096; i += NTHREADS) hist4k[i] = 0u;
        keysel[tid] = ~0ull;
        if (tid == 0) { s_cnt = 0; }
        __syncthreads();                                   // B1

        // ---- one-round fine histogram over key32>>14 (spread bins, no hot addresses) ----
#pragma unroll
        for (int s = 0; s < PER; ++s) {
            unsigned k32 = (unsigned)(v[s] >> 32);
            unsigned bb = k32 >> 14;
            bb = (bb >= BASE14) ? (bb - BASE14) : 0u;
            if (bb > 4095u) bb = 4095u;
            atomicAdd(&hist4k[hloc((int)bb)], 1u);
        }
        __syncthreads();                                   // B2

        // ---- wave0: scan 4096 bins, find boundary bin e with cum >= tgt ----
        if (tid < 64) {
            int l = tid;
            int lanesum = 0;
            for (int q = 0; q < 64; ++q) lanesum += (int)hist4k[q * 64 + l];  // bank-spread
            int incl = lanesum;
#pragma unroll
            for (int off = 1; off < 64; off <<= 1) {
                int y = __shfl_up(incl, off, 64);
                if (l >= off) incl += y;
            }
            int excl = incl - lanesum;
            if (excl < tgt && tgt <= incl) {
                int run = excl, e = 0;
                for (int q = 0; q < 64; ++q) {
                    run += (int)hist4k[q * 64 + l];
                    if (run >= tgt) { e = l * 64 + q; break; }
                }
                s_bin = e; s_C = run;
            }
        }
        __syncthreads();                                   // B3
        int C = s_C;
        unsigned long long T;

        if (C <= CAP) {
            // fast path: chunk = ALL keys in bins <= e (a full-key prefix)
            unsigned k32end = ((BASE14 + (unsigned)s_bin + 1u) << 14) - 1u;
            T = ((unsigned long long)k32end << 32) | 0xFFFFFFFFull;
        } else {
            // ---- exact fallback: byte-wise radix-select of tgt-th smallest ----
            unsigned (*histw)[256] = (unsigned(*)[256])hist4k;
            if (tid == 0) { s_prefix = 0ull; s_target = tgt; s_done = 0; s_findkey = 0; }
            for (int round = 0; round < 10; ++round) {
                __syncthreads();
                if (s_done) break;
                int sh = 56 - 8 * round;
                if (s_findkey) {
                    unsigned long long want = s_prefix; int shh = sh + 8;
#pragma unroll
                    for (int s = 0; s < PER; ++s)
                        if ((v[s] >> shh) == want) { s_T = v[s]; s_done = 1; }
                    continue;
                }
                for (int i = tid; i < NWAVES * 256; i += NTHREADS) ((unsigned*)histw)[i] = 0u;
                __syncthreads();
                unsigned long long pfx = s_prefix;
#pragma unroll
                for (int s = 0; s < PER; ++s) {
                    unsigned long long k = v[s];
                    bool match = (round == 0) || ((k >> (sh + 8)) == pfx);
                    if (match) atomicAdd(&histw[wid][(unsigned)((k >> sh) & 0xFFull)], 1u);
                }
                __syncthreads();
                if (tid < 64) {
                    int l = tid;
                    unsigned c0 = 0, c1 = 0, c2 = 0, c3 = 0;
#pragma unroll
                    for (int w2 = 0; w2 < NWAVES; ++w2) {
                        c0 += histw[w2][4*l+0]; c1 += histw[w2][4*l+1];
                        c2 += histw[w2][4*l+2]; c3 += histw[w2][4*l+3];
                    }
                    unsigned q0 = c0, q1 = q0 + c1, q2 = q1 + c2, q3 = q2 + c3;
                    int lanesum = (int)q3, incl = lanesum;
#pragma unroll
                    for (int off = 1; off < 64; off <<= 1) {
                        int y = __shfl_up(incl, off, 64);
                        if (l >= off) incl += y;
                    }
                    unsigned excl = (unsigned)(incl - lanesum);
                    unsigned tg = (unsigned)s_target;
                    if ((excl < tg) && (tg <= (unsigned)incl)) {
                        unsigned within = tg - excl;
                        int u_; unsigned below, bc;
                        if      (within <= q0) { u_ = 0; below = excl;      bc = c0; }
                        else if (within <= q1) { u_ = 1; below = excl + q0; bc = c1; }
                        else if (within <= q2) { u_ = 2; below = excl + q1; bc = c2; }
                        else                   { u_ = 3; below = excl + q2; bc = c3; }
                        unsigned long long npfx = (pfx << 8) | (unsigned)(4*l + u_);
                        s_target = (int)(tg - below);
                        if (sh == 0) { s_T = npfx; s_done = 1; }
                        else { s_prefix = npfx; if (bc == 1u) s_findkey = 1; }
                    }
                }
            }
            __syncthreads();
            T = s_T;
        }

        // ---- compact keys <= T (consumed keys are ~0, auto-excluded); mark consumed ----
#pragma unroll
        for (int s = 0; s < PER; ++s) {
            unsigned long long k = v[s];
            bool m = (k <= T);
            unsigned long long mask = __ballot(m);
            int basep = 0;
            if (lane == 0 && mask) basep = atomicAdd(&s_cnt, (int)__popcll(mask));
            basep = __shfl(basep, 0, 64);
            if (m) {
                int off = (int)__popcll(mask & ((1ull << lane) - 1ull));
                keysel[basep + off] = k;
                v[s] = ~0ull;
            }
        }
        __syncthreads();                                   // B4
        int cnt = s_cnt;

        // ---- wave0: in-register bitonic sort of 512 keys (8/lane) ----
        if (tid < 64) {
            int b8 = tid * 8;
            unsigned long long w[8];
#pragma unroll
            for (int s = 0; s < 8; ++s) w[s] = keysel[b8 + s];
            auto cex = [&](int si, int ti, bool up) {
                unsigned long long a0 = w[si], c0 = w[ti];
                bool sw = (a0 > c0) == up;
                w[si] = sw ? c0 : a0;
                w[ti] = sw ? a0 : c0;
            };
            for (unsigned k2 = 2; k2 <= (unsigned)CAP; k2 <<= 1) {
                for (unsigned j = k2 >> 1; j; j >>= 1) {
                    if (j >= 8) {
                        bool up = ((b8 & (int)k2) == 0);
                        bool keepmin = (((b8 & (int)j) == 0) == up);
                        int m = (int)(j >> 3);
#pragma unroll
                        for (int s = 0; s < 8; ++s) {
                            unsigned long long p = shfl_xor64(w[s], m);
                            unsigned long long mn = w[s] < p ? w[s] : p;
                            unsigned long long mx = w[s] < p ? p : w[s];
                            w[s] = keepmin ? mn : mx;
                        }
                    } else if (j == 4) {
                        cex(0, 4, ((b8 + 0) & (int)k2) == 0);
                        cex(1, 5, ((b8 + 1) & (int)k2) == 0);
                        cex(2, 6, ((b8 + 2) & (int)k2) == 0);
                        cex(3, 7, ((b8 + 3) & (int)k2) == 0);
                    } else if (j == 2) {
                        cex(0, 2, ((b8 + 0) & (int)k2) == 0);
                        cex(1, 3, ((b8 + 1) & (int)k2) == 0);
                        cex(4, 6, ((b8 + 4) & (int)k2) == 0);
                        cex(5, 7, ((b8 + 5) & (int)k2) == 0);
                    } else { // j == 1
                        cex(0, 1, ((b8 + 0) & (int)k2) == 0);
                        cex(2, 3, ((b8 + 2) & (int)k2) == 0);
                        cex(4, 5, ((b8 + 4) & (int)k2) == 0);
                        cex(6, 7, ((b8 + 6) & (int)k2) == 0);
                    }
                }
            }
#pragma unroll
            for (int s = 0; s < 8; ++s) keysel[b8 + s] = w[s];
        }
        __syncthreads();                                   // B5

        // ---- decode all selected candidates once (tid < cnt) ----
        {
            float x1 = 0, y1 = 0, x2 = 0, y2 = 0, ar = 0, sv = 0;
            if (tid < cnt) {
                unsigned long long key = keysel[tid];
                unsigned idx = (unsigned)(key & 0xFFFFFFFFull);
                float2 l = ((const float2*)lg)[idx];
                float zmax = fmaxf(l.x, l.y), zmin = fminf(l.x, l.y);
                float e = (float)exp((double)(zmin - zmax));
                float den = e + 1.0f;
                sv = (l.y >= l.x) ? (1.0f / den) : (e / den);
                float4 p  = ((const float4*)pp)[idx];
                float4 rr = *(const float4*)(rg + (size_t)idx * 8 + 4);
                float w  = (p.z - p.x) + 1.0f;
                float h  = (p.w - p.y) + 1.0f;
                float cx = p.x + 0.5f * w;
                float cy = p.y + 0.5f * h;
                float dx = rr.x / 10.0f;
                float dy = rr.y / 10.0f;
                float dw = fminf(rr.z / 5.0f, CLIPV);
                float dh = fminf(rr.w / 5.0f, CLIPV);
                float pcx = dx * w + cx;
                float pcy = dy * h + cy;
                float ew = (float)exp((double)dw);
                float eh = (float)exp((double)dh);
                float pw = ew * w;
                float ph = eh * h;
                x1 = pcx - 0.5f * pw;
                y1 = pcy - 0.5f * ph;
                x2 = (pcx + 0.5f * pw) - 1.0f;
                y2 = (pcy + 0.5f * ph) - 1.0f;
                x1 = fminf(fmaxf(x1, 0.0f), 511.0f);
                y1 = fminf(fmaxf(y1, 0.0f), 511.0f);
                x2 = fminf(fmaxf(x2, 0.0f), 511.0f);
                y2 = fminf(fmaxf(y2, 0.0f), 511.0f);
                ar = ((x2 - x1) + 1.0f) * ((y2 - y1) + 1.0f);
            }
            bx1s[tid] = x1; by1s[tid] = y1; bx2s[tid] = x2; by2s[tid] = y2;
            bars[tid] = ar; bscs[tid] = sv;
        }
        __syncthreads();                                   // B6

        // ---- tiled greedy NMS over this chunk ----
        for (int i0 = 0; i0 < cnt && kept < DETS; i0 += 64) {
            if (tid < 64) supk[tid] = (i0 + tid < cnt) ? 0u : 1u;
            else if (tid < 192) { int q = tid - 64; tmask[q >> 1][q & 1] = 0u; }
            __syncthreads();

            // candidate vs already-kept (8 slices)
            {
                int cc = tid & 63, sl = tid >> 6;
                if (supk[cc] == 0u) {
                    int gi = i0 + cc;
                    float x1 = bx1s[gi], y1 = by1s[gi], x2 = bx2s[gi], y2 = by2s[gi], ar = bars[gi];
                    for (int s2 = sl; s2 < kept; s2 += 8) {
                        float iou = iou_f(kb[0][s2], kb[1][s2], kb[2][s2], kb[3][s2], kb[4][s2],
                                          x1, y1, x2, y2, ar);
                        if (iou > 0.5f) { supk[cc] = 1u; break; }
                    }
                }
            }
            // intra-tile 64x64 suppression rows
            {
                int i = tid >> 3, jb = (tid & 7) << 3;
                int gi = i0 + i;
                float x1 = bx1s[gi], y1 = by1s[gi], x2 = bx2s[gi], y2 = by2s[gi], ar = bars[gi];
                unsigned byte = 0;
#pragma unroll
                for (int u = 0; u < 8; ++u) {
                    int j = jb + u;
                    if (j > i) {
                        int gj = i0 + j;
                        float iou = iou_f(x1, y1, x2, y2, ar,
                                          bx1s[gj], by1s[gj], bx2s[gj], by2s[gj], bars[gj]);
                        if (iou > 0.5f) byte |= (1u << u);
                    }
                }
                if (byte) atomicOr(&tmask[i][jb >> 5], byte << (jb & 31));
            }
            __syncthreads();

            // wave0: greedy resolve (skip non-suppressors)
            if (tid < 64) {
                int l = tid;
                unsigned long long row = ((unsigned long long)tmask[l][1] << 32) | tmask[l][0];
                int alive0 = supk[l] ? 0 : 1;
                unsigned long long aliveMask = __ballot(alive0);
                unsigned long long pend = __ballot(alive0 && row != 0ull);
                while (pend) {
                    int c = __ffsll(pend) - 1;
                    unsigned long long rc = shfl_bc64(row, c);
                    aliveMask &= ~rc;                // rc only has bits > c
                    pend &= ~(1ull << c);
                    pend &= aliveMask;
                }
                int alive = (int)((aliveMask >> l) & 1ull);
                int rank = kept + (int)__popcll(aliveMask & ((1ull << l) - 1ull));
                int gi = i0 + l;
                if (alive) {
                    if (rank < DETS) {
                        float* o = obox + rank * 5;
                        o[0] = bx1s[gi]; o[1] = by1s[gi]; o[2] = bx2s[gi]; o[3] = by2s[gi];
                        o[4] = bscs[gi];
                        olab[rank] = 1.0f;
                        oval[rank] = 1.0f;
                    }
                    kb[0][rank] = bx1s[gi]; kb[1][rank] = by1s[gi];
                    kb[2][rank] = bx2s[gi]; kb[3][rank] = by2s[gi];
                    kb[4][rank] = bars[gi];
                }
                if (l == 0) s_kept = kept + (int)__popcll(aliveMask);
            }
            __syncthreads();
            kept = s_kept;
        }

        Mdone += cnt;
    }

    // ---------------- zero-fill remaining output rows ----------------
    int start = kept < DETS ? kept : DETS;
    for (int c2 = start + tid; c2 < DETS; c2 += NTHREADS) {
        float* o = obox + c2 * 5;
        o[0] = 0.0f; o[1] = 0.0f; o[2] = 0.0f; o[3] = 0.0f; o[4] = 0.0f;
        olab[c2] = 0.0f;
        oval[c2] = 0.0f;
    }
}

extern "C" void kernel_launch(void* const* d_in, const int* in_sizes, int n_in,
                              void* d_out, int out_size, void* d_ws, size_t ws_size,
                              hipStream_t stream) {
    (void)d_ws; (void)ws_size; (void)n_in;
    const float* logits = (const float*)d_in[0];
    const float* regr   = (const float*)d_in[1];
    const float* props  = (const float*)d_in[2];
    float* out = (float*)d_out;

    int B = out_size / 700;          // (100*5 + 100 + 100) per image
    if (B < 1) B = 1;
    int N = in_sizes[0] / (2 * B);   // logits = B*N*2

    postproc_kernel<<<B, NTHREADS, 0, stream>>>(logits, regr, props, out, B, N);
}

// Round 7
// 21.261 us; speedup vs baseline: 1.6028x; 1.6028x over previous
//
#include <hip/hip_runtime.h>
#include <math.h>

#define NTHREADS 512
#define MAXN 4096
#define PER 8            // keys per thread = MAXN / NTHREADS
#define DETS 100
#define CHUNK 256        // per-round selection target
#define CAP 512          // chunk capacity
#define NWAVES (NTHREADS / 64)

static __device__ __forceinline__ unsigned long long shfl_bc64(unsigned long long x, int src) {
    int lo = __shfl((int)(unsigned)x, src, 64);
    int hi = __shfl((int)(unsigned)(x >> 32), src, 64);
    return ((unsigned long long)(unsigned)hi << 32) | (unsigned)lo;
}

static __device__ __forceinline__ float iou_f(float ax1, float ay1, float ax2, float ay2, float aar,
                                              float bx1, float by1, float bx2, float by2, float bar) {
#pragma clang fp contract(off)
    float xx1 = fmaxf(ax1, bx1), yy1 = fmaxf(ay1, by1);
    float xx2 = fminf(ax2, bx2), yy2 = fminf(ay2, by2);
    float iw = fmaxf((xx2 - xx1) + 1.0f, 0.0f);
    float ih = fmaxf((yy2 - yy1) + 1.0f, 0.0f);
    float inter = iw * ih;
    return inter / ((aar + bar) - inter);
}

__global__ __launch_bounds__(NTHREADS) void postproc_kernel(
    const float* __restrict__ logits,   // (B,N,2)
    const float* __restrict__ regr,     // (B,N,8)
    const float* __restrict__ props,    // (B,N,4)
    float* __restrict__ out,            // (B,100,5) ++ (B,100) ++ (B,100)
    int B, int N)
{
#pragma clang fp contract(off)
    const int b    = blockIdx.x;
    const int tid  = threadIdx.x;
    const int lane = tid & 63;
    const int wid  = tid >> 6;

    __shared__ __align__(16) unsigned long long keysel[CAP];   // 4 KB (unsorted chunk)
    __shared__ unsigned hist4k[4096];                          // 16 KB (linear layout)
    __shared__ unsigned s_super[64];
    __shared__ float bx1s[CAP], by1s[CAP], bx2s[CAP], by2s[CAP], bars[CAP], bscs[CAP]; // 12 KB
    __shared__ float kb[5][DETS + 64];
    __shared__ unsigned tmask[64][2];
    __shared__ unsigned supk[64];
    __shared__ int s_kept, s_cnt, s_C;
    __shared__ unsigned long long s_prefix, s_T;
    __shared__ int s_target, s_done, s_findkey;

    const float* lg = logits + (size_t)b * N * 2;
    const float* rg = regr   + (size_t)b * N * 8;
    const float* pp = props  + (size_t)b * N * 4;

    // ---------------- Phase A: keys in registers (coalesced loads) ----------------
    unsigned long long v[PER];
#pragma unroll
    for (int s = 0; s < PER; ++s) {
        int a = s * NTHREADS + tid;
        unsigned long long key;
        if (a < N) {
            float2 l = ((const float2*)lg)[a];
            // softmax[:,1] bit-exact: one exp arg is exactly 0 -> e=1
            float zmax = fmaxf(l.x, l.y), zmin = fminf(l.x, l.y);
            float e   = (float)exp((double)(zmin - zmax));
            float den = e + 1.0f;
            float sscore = (l.y >= l.x) ? (1.0f / den) : (e / den);
            float f = (sscore > 0.05f) ? sscore : -1e30f;
            unsigned u = __float_as_uint(f);
            u = (u & 0x80000000u) ? ~u : (u | 0x80000000u);     // monotone float->uint
            key = ((unsigned long long)(~u) << 32) | (unsigned)a; // small key = best
        } else key = ~0ull;
        v[s] = key;
    }
    if (tid == 0) s_kept = 0;

    float* obox = out + (size_t)b * DETS * 5;
    float* olab = out + (size_t)B * DETS * 5 + (size_t)b * DETS;
    float* oval = out + (size_t)B * DETS * 5 + (size_t)B * DETS + (size_t)b * DETS;
    const float CLIPV = (float)4.135166556742356;   // log(1000/16)

    int kept = 0;

    while (kept < DETS) {
        // ---- zero hist + counters ----
        for (int i = tid; i < 4096; i += NTHREADS) hist4k[i] = 0u;
        if (tid == 0) { s_cnt = 0; s_C = 0; }
        __syncthreads();                                   // B1

        // ---- one-round histogram: 12-bit-ish digit = (key32>>18) - 0x1000 ----
        // valid keys (score in (0.05,1]) -> key32 in [0x407FFFFF,0x42B33332]
        // -> bins [0x1F,0xAC]; invalid/consumed clamp to 4095.
#pragma unroll
        for (int s = 0; s < PER; ++s) {
            unsigned hb = (unsigned)(v[s] >> 50) - 0x1000u;   // (key32>>18)-0x1000
            if (hb > 4094u) hb = 4095u;
            atomicAdd(&hist4k[hb], 1u);
        }
        __syncthreads();                                   // B2

        // ---- super-bin sums (64 supers x 64 bins), all threads ----
        {
            unsigned p = 0;
            int base8 = tid * 8;
#pragma unroll
            for (int u = 0; u < 8; ++u) p += hist4k[base8 + u];
#pragma unroll
            for (int off = 4; off; off >>= 1) p += __shfl_down(p, off, 8);
            if ((tid & 7) == 0) s_super[tid >> 3] = p;
        }
        __syncthreads();                                   // B3

        // ---- wave0: two-level cumsum -> boundary bin, C, T ----
        if (tid < 64) {
            int l = tid;
            int sp = (int)s_super[l];
            int incl = sp;
#pragma unroll
            for (int off = 1; off < 64; off <<= 1) {
                int y = __shfl_up(incl, off, 64);
                if (l >= off) incl += y;
            }
            int total = __shfl(incl, 63, 64);
            int inv   = (int)hist4k[4095];
            int W     = total - inv;                      // remaining valid keys
            if (W > 0) {
                int tgt2 = W < CHUNK ? W : CHUNK;
                int excl = incl - sp;
                bool hit = (excl < tgt2) && (tgt2 <= incl);
                unsigned long long bm = __ballot(hit);
                int E = __ffsll(bm) - 1;
                int prevCum = __shfl(excl, E, 64);
                // inner level: 64 bins of super E
                int c2 = (int)hist4k[E * 64 + l];
                int incl2 = c2;
#pragma unroll
                for (int off = 1; off < 64; off <<= 1) {
                    int y = __shfl_up(incl2, off, 64);
                    if (l >= off) incl2 += y;
                }
                int cum2 = prevCum + incl2;
                int excl2 = cum2 - c2;
                bool hit2 = (excl2 < tgt2) && (tgt2 <= cum2);
                if (hit2) {
                    int bin = E * 64 + l;
                    unsigned k32end = ((0x1000u + (unsigned)bin + 1u) << 18) - 1u;
                    s_T = ((unsigned long long)k32end << 32) | 0xFFFFFFFFull;
                    s_C = cum2;
                    s_target = tgt2;                      // for fallback
                }
            }
        }
        __syncthreads();                                   // B4
        int C = s_C;
        if (C == 0) break;                                 // no valid keys left

        if (C > CAP) {
            // ---- exact fallback: byte-wise radix-select of target-th smallest ----
            unsigned (*histw)[256] = (unsigned(*)[256])hist4k;
            if (tid == 0) { s_prefix = 0ull; s_done = 0; s_findkey = 0; }
            for (int round = 0; round < 10; ++round) {
                __syncthreads();
                if (s_done) break;
                int sh = 56 - 8 * round;
                if (s_findkey) {
                    unsigned long long want = s_prefix; int shh = sh + 8;
#pragma unroll
                    for (int s = 0; s < PER; ++s)
                        if ((v[s] >> shh) == want) { s_T = v[s]; s_done = 1; }
                    continue;
                }
                for (int i = tid; i < NWAVES * 256; i += NTHREADS) ((unsigned*)histw)[i] = 0u;
                __syncthreads();
                unsigned long long pfx = s_prefix;
#pragma unroll
                for (int s = 0; s < PER; ++s) {
                    unsigned long long k = v[s];
                    bool match = (round == 0) || ((k >> (sh + 8)) == pfx);
                    if (match) atomicAdd(&histw[wid][(unsigned)((k >> sh) & 0xFFull)], 1u);
                }
                __syncthreads();
                if (tid < 64) {
                    int l = tid;
                    unsigned c0 = 0, c1 = 0, c2 = 0, c3 = 0;
#pragma unroll
                    for (int w2 = 0; w2 < NWAVES; ++w2) {
                        c0 += histw[w2][4*l+0]; c1 += histw[w2][4*l+1];
                        c2 += histw[w2][4*l+2]; c3 += histw[w2][4*l+3];
                    }
                    unsigned q0 = c0, q1 = q0 + c1, q2 = q1 + c2, q3 = q2 + c3;
                    int lanesum = (int)q3, incl = lanesum;
#pragma unroll
                    for (int off = 1; off < 64; off <<= 1) {
                        int y = __shfl_up(incl, off, 64);
                        if (l >= off) incl += y;
                    }
                    unsigned excl = (unsigned)(incl - lanesum);
                    unsigned tg = (unsigned)s_target;
                    if ((excl < tg) && (tg <= (unsigned)incl)) {
                        unsigned within = tg - excl;
                        int u_; unsigned below, bc;
                        if      (within <= q0) { u_ = 0; below = excl;      bc = c0; }
                        else if (within <= q1) { u_ = 1; below = excl + q0; bc = c1; }
                        else if (within <= q2) { u_ = 2; below = excl + q1; bc = c2; }
                        else                   { u_ = 3; below = excl + q2; bc = c3; }
                        unsigned long long npfx = (pfx << 8) | (unsigned)(4*l + u_);
                        s_target = (int)(tg - below);
                        if (sh == 0) { s_T = npfx; s_done = 1; }
                        else { s_prefix = npfx; if (bc == 1u) s_findkey = 1; }
                    }
                }
            }
            __syncthreads();
        }
        unsigned long long T = s_T;

        // ---- compact keys <= T (consumed keys ~0 auto-excluded); mark consumed ----
#pragma unroll
        for (int s = 0; s < PER; ++s) {
            unsigned long long k = v[s];
            bool m = (k <= T);
            unsigned long long mask = __ballot(m);
            int basep = 0;
            if (lane == 0 && mask) basep = atomicAdd(&s_cnt, (int)__popcll(mask));
            basep = __shfl(basep, 0, 64);
            if (m) {
                int off = (int)__popcll(mask & ((1ull << lane) - 1ull));
                keysel[basep + off] = k;
                v[s] = ~0ull;
            }
        }
        __syncthreads();                                   // B5
        int cnt = s_cnt;

        // ---- fused rank-counting sort + decode (depth-1, gather latency hidden) ----
        if (tid < cnt) {
            unsigned long long myk = keysel[tid];
            unsigned idx = (unsigned)(myk & 0xFFFFFFFFull);
            // issue gathers first; rank loop below hides their latency
            float2 l  = ((const float2*)lg)[idx];
            float4 p  = ((const float4*)pp)[idx];
            float4 rr = *(const float4*)(rg + (size_t)idx * 8 + 4);
            // rank = #{keys < myk} among chunk (keys unique)
            int r = 0;
            const ulonglong2* kp2 = (const ulonglong2*)keysel;
            int half = cnt >> 1;
            for (int j = 0; j < half; ++j) {
                ulonglong2 two = kp2[j];
                r += (two.x < myk) ? 1 : 0;
                r += (two.y < myk) ? 1 : 0;
            }
            if (cnt & 1) r += (keysel[cnt - 1] < myk) ? 1 : 0;
            // decode (ref float32 op order, no FMA)
            float zmax = fmaxf(l.x, l.y), zmin = fminf(l.x, l.y);
            float e = (float)exp((double)(zmin - zmax));
            float den = e + 1.0f;
            float sv = (l.y >= l.x) ? (1.0f / den) : (e / den);
            float w  = (p.z - p.x) + 1.0f;
            float h  = (p.w - p.y) + 1.0f;
            float cx = p.x + 0.5f * w;
            float cy = p.y + 0.5f * h;
            float dx = rr.x / 10.0f;
            float dy = rr.y / 10.0f;
            float dw = fminf(rr.z / 5.0f, CLIPV);
            float dh = fminf(rr.w / 5.0f, CLIPV);
            float pcx = dx * w + cx;
            float pcy = dy * h + cy;
            float ew = (float)exp((double)dw);
            float eh = (float)exp((double)dh);
            float pw = ew * w;
            float ph = eh * h;
            float x1 = pcx - 0.5f * pw;
            float y1 = pcy - 0.5f * ph;
            float x2 = (pcx + 0.5f * pw) - 1.0f;
            float y2 = (pcy + 0.5f * ph) - 1.0f;
            x1 = fminf(fmaxf(x1, 0.0f), 511.0f);
            y1 = fminf(fmaxf(y1, 0.0f), 511.0f);
            x2 = fminf(fmaxf(x2, 0.0f), 511.0f);
            y2 = fminf(fmaxf(y2, 0.0f), 511.0f);
            bx1s[r] = x1; by1s[r] = y1; bx2s[r] = x2; by2s[r] = y2;
            bars[r] = ((x2 - x1) + 1.0f) * ((y2 - y1) + 1.0f);
            bscs[r] = sv;
        }
        __syncthreads();                                   // B6

        // ---- tiled greedy NMS over this chunk (sorted order) ----
        for (int i0 = 0; i0 < cnt && kept < DETS; i0 += 64) {
            if (tid < 64) supk[tid] = (i0 + tid < cnt) ? 0u : 1u;
            else if (tid < 192) { int q = tid - 64; tmask[q >> 1][q & 1] = 0u; }
            __syncthreads();

            // candidate vs already-kept (8 slices)
            {
                int cc = tid & 63, sl = tid >> 6;
                if (supk[cc] == 0u) {
                    int gi = i0 + cc;
                    float x1 = bx1s[gi], y1 = by1s[gi], x2 = bx2s[gi], y2 = by2s[gi], ar = bars[gi];
                    for (int s2 = sl; s2 < kept; s2 += 8) {
                        float iou = iou_f(kb[0][s2], kb[1][s2], kb[2][s2], kb[3][s2], kb[4][s2],
                                          x1, y1, x2, y2, ar);
                        if (iou > 0.5f) { supk[cc] = 1u; break; }
                    }
                }
            }
            // intra-tile 64x64 suppression rows
            {
                int i = tid >> 3, jb = (tid & 7) << 3;
                int gi = i0 + i;
                float x1 = bx1s[gi], y1 = by1s[gi], x2 = bx2s[gi], y2 = by2s[gi], ar = bars[gi];
                unsigned byte = 0;
#pragma unroll
                for (int u = 0; u < 8; ++u) {
                    int j = jb + u;
                    if (j > i) {
                        int gj = i0 + j;
                        float iou = iou_f(x1, y1, x2, y2, ar,
                                          bx1s[gj], by1s[gj], bx2s[gj], by2s[gj], bars[gj]);
                        if (iou > 0.5f) byte |= (1u << u);
                    }
                }
                if (byte) atomicOr(&tmask[i][jb >> 5], byte << (jb & 31));
            }
            __syncthreads();

            // wave0: greedy resolve (skip non-suppressors)
            if (tid < 64) {
                int l = tid;
                unsigned long long row = ((unsigned long long)tmask[l][1] << 32) | tmask[l][0];
                int alive0 = supk[l] ? 0 : 1;
                unsigned long long aliveMask = __ballot(alive0);
                unsigned long long pend = __ballot(alive0 && row != 0ull);
                while (pend) {
                    int c = __ffsll(pend) - 1;
                    unsigned long long rc = shfl_bc64(row, c);
                    aliveMask &= ~rc;                // rc only has bits > c
                    pend &= ~(1ull << c);
                    pend &= aliveMask;
                }
                int alive = (int)((aliveMask >> l) & 1ull);
                int rank = kept + (int)__popcll(aliveMask & ((1ull << l) - 1ull));
                int gi = i0 + l;
                if (alive) {
                    if (rank < DETS) {
                        float* o = obox + rank * 5;
                        o[0] = bx1s[gi]; o[1] = by1s[gi]; o[2] = bx2s[gi]; o[3] = by2s[gi];
                        o[4] = bscs[gi];
                        olab[rank] = 1.0f;
                        oval[rank] = 1.0f;
                    }
                    kb[0][rank] = bx1s[gi]; kb[1][rank] = by1s[gi];
                    kb[2][rank] = bx2s[gi]; kb[3][rank] = by2s[gi];
                    kb[4][rank] = bars[gi];
                }
                if (l == 0) s_kept = kept + (int)__popcll(aliveMask);
            }
            __syncthreads();
            kept = s_kept;
        }
    }

    // ---------------- zero-fill remaining output rows ----------------
    int start = kept < DETS ? kept : DETS;
    for (int c2 = start + tid; c2 < DETS; c2 += NTHREADS) {
        float* o = obox + c2 * 5;
        o[0] = 0.0f; o[1] = 0.0f; o[2] = 0.0f; o[3] = 0.0f; o[4] = 0.0f;
        olab[c2] = 0.0f;
        oval[c2] = 0.0f;
    }
}

extern "C" void kernel_launch(void* const* d_in, const int* in_sizes, int n_in,
                              void* d_out, int out_size, void* d_ws, size_t ws_size,
                              hipStream_t stream) {
    (void)d_ws; (void)ws_size; (void)n_in;
    const float* logits = (const float*)d_in[0];
    const float* regr   = (const float*)d_in[1];
    const float* props  = (const float*)d_in[2];
    float* out = (float*)d_out;

    int B = out_size / 700;          // (100*5 + 100 + 100) per image
    if (B < 1) B = 1;
    int N = in_sizes[0] / (2 * B);   // logits = B*N*2

    postproc_kernel<<<B, NTHREADS, 0, stream>>>(logits, regr, props, out, B, N);
}